// Round 10
// baseline (242.087 us; speedup 1.0000x reference)
//
#include <hip/hip_runtime.h>

#define NIVL  256
#define KINV  51.2f        // 256/5
#define KSTEP 0.01953125f  // 5/256 (exact in fp32)
#define TPW   7168
#define BCAP  256          // max edges per L-bin (avg 128)
#define DCAP  64           // max edges per dst node (avg 8)
#define NROW  11           // distinct t-rows
#define TSTR  40           // u-stride (pad 32->40)
#define TPACK 448          // T-build+pack blocks: 64 k-groups x 7 w-slices
#define GRID  512

typedef __attribute__((ext_vector_type(8))) __bf16 bf16x8;
typedef __attribute__((ext_vector_type(4))) float f32x4;
union FragU { uint4 u; bf16x8 v; };

__device__ __forceinline__ float sigmoidf_(float v) { return 1.f / (1.f + expf(-v)); }
__device__ __forceinline__ unsigned bf16r_(float x) { return (__float_as_uint(x) + 0x8000u) >> 16; }
__device__ __forceinline__ unsigned pk_(float lo, float hi) { return (bf16r_(hi) << 16) | bf16r_(lo); }

__device__ __forceinline__ f32x4 mfma_(bf16x8 a, bf16x8 b, f32x4 c) {
    return __builtin_amdgcn_mfma_f32_16x16x32_bf16(a, b, c, 0, 0, 0);
}

// Device-scope software grid barrier. Correct because all GRID blocks are
// co-resident (LB(256,2) + 28.3KB LDS -> exactly 2 blocks/CU x 256 CU = 512).
// threadfence release (L2 wb) before arrive; acquire (L2 inv) after spin --
// required since per-XCD L2s are not cross-coherent.
__device__ __forceinline__ void gbar(int* cnt, int target) {
    __syncthreads();
    if (threadIdx.x == 0) {
        __threadfence();
        __hip_atomic_fetch_add(cnt, 1, __ATOMIC_RELAXED, __HIP_MEMORY_SCOPE_AGENT);
        while (__hip_atomic_load(cnt, __ATOMIC_RELAXED, __HIP_MEMORY_SCOPE_AGENT) < target)
            __builtin_amdgcn_s_sleep(2);
        __threadfence();
    }
    __syncthreads();
}

union SharedU {
    struct { float hk[5][64]; float Tsl[5][1024]; } p1;                 // 21.8 KB
    struct { __align__(16) unsigned short TB[2 * NROW * 16 * TSTR];
             float ECF[32]; } p2;                                       // 28.3 KB
    float ms[8][160];                                                   // 5 KB
};

__global__ __launch_bounds__(256, 2)
void mega_kernel(const float* __restrict__ x, const float* __restrict__ ea,
                 const float* __restrict__ elen, const int* __restrict__ esrc,
                 const int* __restrict__ edst, const float* __restrict__ W1,
                 const float* __restrict__ W2, const float* __restrict__ Wss,
                 const float* __restrict__ Wsv, float* __restrict__ out,
                 uint4* __restrict__ Bpk, float* __restrict__ msg,
                 float* __restrict__ erec, int* __restrict__ cntL,
                 int* __restrict__ cntD, int* __restrict__ sortedD,
                 int* __restrict__ bar, int N, int E)
{
    __shared__ SharedU sh;
    const int tid = threadIdx.x;
    const int vb = blockIdx.x;

    // ============ PHASE A: T-build(5 knots)+pack | edge scatter =============
    if (vb < TPACK) {
        const int bx = vb % 7;
        const int k0 = (vb / 7) * 4;
        for (int idx = tid; idx < 320; idx += 256) {
            int kk = idx >> 6, c = idx & 63;
            float L = (float)(k0 + kk) * KSTEP;
            float d = 0.f;
#pragma unroll
            for (int r = 0; r < 8; ++r) {
                float dd = L - (float)r * (5.f / 7.f);
                d += expf(-dd * dd * 0.98f) * W1[r * 64 + c];
            }
            d *= 0.3535533906f;
            sh.p1.hk[kk][c] = d * sigmoidf_(d) * 0.125f;
        }
        __syncthreads();
        float4 acc[5];
#pragma unroll
        for (int q = 0; q < 5; ++q) acc[q] = make_float4(0.f, 0.f, 0.f, 0.f);
        const int pw = bx * 1024 + tid * 4;
#pragma unroll 4
        for (int c = 0; c < 64; ++c) {
            float4 w4 = *(const float4*)(W2 + (size_t)c * TPW + pw);
#pragma unroll
            for (int q = 0; q < 5; ++q) {
                float hv = sh.p1.hk[q][c];
                acc[q].x = fmaf(hv, w4.x, acc[q].x);
                acc[q].y = fmaf(hv, w4.y, acc[q].y);
                acc[q].z = fmaf(hv, w4.z, acc[q].z);
                acc[q].w = fmaf(hv, w4.w, acc[q].w);
            }
        }
        __syncthreads();
#pragma unroll
        for (int q = 0; q < 5; ++q)
            *(float4*)&sh.p1.Tsl[q][tid * 4] = acc[q];
        __syncthreads();
        const int lane_s = tid & 63, whs = (tid >> 6) & 1, ih = tid >> 7;
        const int u0p = (lane_s >> 4) * 8, wp = whs * 16 + (lane_s & 15);
#pragma unroll
        for (int t2 = 0; t2 < 2; ++t2) {
            const int jj = k0 + ih + t2 * 2;
            const int kk = jj - k0;
            unsigned ta[4], dd[4];
#pragma unroll
            for (int q = 0; q < 4; ++q) {
                float a0 = sh.p1.Tsl[kk][(u0p + 2 * q) * 32 + wp];
                float a1 = sh.p1.Tsl[kk][(u0p + 2 * q + 1) * 32 + wp];
                float b0 = sh.p1.Tsl[kk + 1][(u0p + 2 * q) * 32 + wp];
                float b1 = sh.p1.Tsl[kk + 1][(u0p + 2 * q + 1) * 32 + wp];
                ta[q] = pk_(a0, a1);
                dd[q] = pk_(b0 - a0, b1 - a1);
            }
            Bpk[((size_t)jj * 28 + bx * 4 + whs) * 64 + lane_s]     = make_uint4(ta[0], ta[1], ta[2], ta[3]);
            Bpk[((size_t)jj * 28 + bx * 4 + 2 + whs) * 64 + lane_s] = make_uint4(dd[0], dd[1], dd[2], dd[3]);
        }
    } else {
        const float I3 = 0.5773502692f, I5 = 0.4472135955f, S2 = 0.7071067812f;
        const float I6 = 0.4082482905f, T6 = 0.8164965809f;
        for (int e = (vb - TPACK) * 256 + tid; e < E; e += (GRID - TPACK) * 256) {
            float t = elen[e] * KINV;
            int j = (int)t; j = j > 255 ? 255 : j;
            int pos = atomicAdd(&cntL[j], 1);
            if (pos < BCAP) {
                const float* y = ea + (size_t)e * 9;
                float y0 = y[0];
                float a = y[4], b = y[5], c = y[6], d2 = y[7], ee = y[8];
                float4 r0, r1, r2, r3;
                r0.x = t - (float)j;
                r0.y = __int_as_float(esrc[e]);
                r0.z = 0.f;
                r0.w = y0;
                r1.x = y0 * I3;
                r1.y = y[1] * I3; r1.z = y[2] * I3; r1.w = y[3] * I3;
                r2.x = (-c * I6 + ee * S2) * I5;
                r2.y = a * S2 * I5;
                r2.z = d2 * S2 * I5;
                r2.w = (-c * I6 - ee * S2) * I5;
                r3.x = b * S2 * I5;
                r3.y = c * T6 * I5;
                r3.z = 0.f; r3.w = 0.f;
                float4* dst = (float4*)(erec + ((size_t)j * BCAP + pos) * 16);
                dst[0] = r0; dst[1] = r1; dst[2] = r2; dst[3] = r3;
            }
            int slot = j * BCAP + (pos < BCAP ? pos : BCAP - 1);
            int d = edst[e];
            int pd = atomicAdd(&cntD[d], 1);
            if (pd < DCAP) sortedD[d * DCAP + pd] = slot;
        }
    }

    gbar(&bar[0], GRID);   // Bpk/erec/cntL/cntD/sortedD visible device-wide

    // ============ PHASE B: fold (R8 structure, j = vb>>1) ===================
    {
        const int j = vb >> 1, half = vb & 1;
        const int cnt = min(cntL[j], BCAP);
        const int nchunk = (cnt + 31) >> 5;
        const int te = tid & 31, sub = tid >> 5;
        const int wv = tid >> 6, lane = tid & 63;
        const int sg = wv >> 1, wh = wv & 1;
        const int col = lane & 15, quad = lane >> 4;

        float4 er0 = {0,0,0,0}, er1 = {0,0,0,0}, er2 = {0,0,0,0}, er3 = {0,0,0,0};
        if (half < nchunk) {
            int ce = min(32, cnt - (half << 5));
            if (te < ce) {
                const float4* rp = (const float4*)(erec + ((size_t)j * BCAP + (half << 5) + te) * 16);
                er0 = rp[0]; er1 = rp[1]; er2 = rp[2]; er3 = rp[3];
            }
        }

        bf16x8 Bt[7][2];
        {
            const uint4* bp = Bpk + (size_t)j * 28 * 64 + lane;
#pragma unroll
            for (int pl = 0; pl < 7; ++pl) {
                FragU fa; fa.u = bp[(pl * 4 + wh) * 64];     Bt[pl][0] = fa.v;
                FragU fd; fd.u = bp[(pl * 4 + 2 + wh) * 64]; Bt[pl][1] = fd.v;
            }
        }

        const float A0 = 0.125f, A1 = 0.1767766953f;

        for (int ci = half; ci < nchunk; ci += 2) {
            const int base = ci << 5;
            const int cntE = min(32, cnt - base);

            const int u0 = sub * 4;
            float s4[4], vvx[12];
            if (te < cntE) {
                int src = __float_as_int(er0.y);
                const float* xp = x + (size_t)src * 128;
                *(float4*)s4 = *(const float4*)(xp + u0);
                *(float4*)(vvx)     = *(const float4*)(xp + 32 + 3 * u0);
                *(float4*)(vvx + 4) = *(const float4*)(xp + 32 + 3 * u0 + 4);
                *(float4*)(vvx + 8) = *(const float4*)(xp + 32 + 3 * u0 + 8);
            }
            float4 nr0 = {0,0,0,0}, nr1 = {0,0,0,0}, nr2 = {0,0,0,0}, nr3 = {0,0,0,0};
            const int cin = ci + 2;
            if (cin < nchunk) {
                int ce2 = min(32, cnt - (cin << 5));
                if (te < ce2) {
                    const float4* rp = (const float4*)(erec + ((size_t)j * BCAP + (cin << 5) + te) * 16);
                    nr0 = rp[0]; nr1 = rp[1]; nr2 = rp[2]; nr3 = rp[3];
                }
            }

            __syncthreads();

            {
                const int esg = te >> 4, e16 = te & 15;
                float rv[NROW][4];
                if (te < cntE) {
                    float y0 = er0.w;
                    float y0i = er1.x, y1i0 = er1.y, y1i1 = er1.z, y1i2 = er1.w;
                    float M0 = er2.x, M1 = er2.y, M2 = er2.z, M4 = er2.w;
                    float M5 = er3.x, M8 = er3.y;
                    if (sub == 0) sh.p2.ECF[te] = er0.x;
#pragma unroll
                    for (int up = 0; up < 4; ++up) {
                        float s = s4[up];
                        float v0 = vvx[3 * up], v1 = vvx[3 * up + 1], v2 = vvx[3 * up + 2];
                        rv[0][up] = s * y0;
                        rv[1][up] = v0 * y1i0 + v1 * y1i1 + v2 * y1i2;
                        rv[2][up] = s * y1i0;
                        rv[3][up] = s * y1i1;
                        rv[4][up] = s * y1i2;
                        rv[5][up] = v0 * y0i;
                        rv[6][up] = v1 * y0i;
                        rv[7][up] = v2 * y0i;
                        rv[8][up]  = v0 * M0 + v1 * M1 + v2 * M2;
                        rv[9][up]  = v0 * M1 + v1 * M4 + v2 * M5;
                        rv[10][up] = v0 * M2 + v1 * M5 + v2 * M8;
                    }
                } else {
#pragma unroll
                    for (int r = 0; r < NROW; ++r)
#pragma unroll
                        for (int up = 0; up < 4; ++up) rv[r][up] = 0.f;
                }
#pragma unroll
                for (int r = 0; r < NROW; ++r) {
                    unsigned lo = pk_(rv[r][0], rv[r][1]);
                    unsigned hi = pk_(rv[r][2], rv[r][3]);
                    *(uint2*)&sh.p2.TB[((esg * NROW + r) * 16 + e16) * TSTR + u0] = make_uint2(lo, hi);
                }
            }
            __syncthreads();

            f32x4 cS0 = {0,0,0,0}, cS1 = {0,0,0,0}, cG0 = {0,0,0,0}, cG1 = {0,0,0,0};
            f32x4 cV[3][2];
#pragma unroll
            for (int k = 0; k < 3; ++k) { cV[k][0] = (f32x4){0,0,0,0}; cV[k][1] = (f32x4){0,0,0,0}; }

            #define LOADA(r) ({ FragU fa_; fa_.u = *(const uint4*)&sh.p2.TB[((sg * NROW + (r)) * 16 + col) * TSTR + quad * 8]; fa_.v; })

            bf16x8 a0 = LOADA(0), a1 = LOADA(1);
            cS0 = mfma_(a0, Bt[0][0], cS0); cS0 = mfma_(a1, Bt[1][0], cS0);
            cS1 = mfma_(a0, Bt[0][1], cS1); cS1 = mfma_(a1, Bt[1][1], cS1);
            cG0 = mfma_(a0, Bt[2][0], cG0); cG0 = mfma_(a1, Bt[3][0], cG0);
            cG1 = mfma_(a0, Bt[2][1], cG1); cG1 = mfma_(a1, Bt[3][1], cG1);
#pragma unroll
            for (int k = 0; k < 3; ++k) {
                bf16x8 ak;
                ak = LOADA(2 + k);
                cV[k][0] = mfma_(ak, Bt[4][0], cV[k][0]);
                cV[k][1] = mfma_(ak, Bt[4][1], cV[k][1]);
                ak = LOADA(5 + k);
                cV[k][0] = mfma_(ak, Bt[5][0], cV[k][0]);
                cV[k][1] = mfma_(ak, Bt[5][1], cV[k][1]);
                ak = LOADA(8 + k);
                cV[k][0] = mfma_(ak, Bt[6][0], cV[k][0]);
                cV[k][1] = mfma_(ak, Bt[6][1], cV[k][1]);
            }

            const int w = wh * 16 + col;
            const int sbase = j * BCAP + base;
#pragma unroll
            for (int reg = 0; reg < 4; ++reg) {
                int e = sg * 16 + quad * 4 + reg;
                if (e < cntE) {
                    float f = sh.p2.ECF[e];
                    float* mp = msg + (size_t)(sbase + e) * 160;
                    mp[w]            = (cS0[reg] + f * cS1[reg]) * A0;
                    mp[32 + w]       = (cG0[reg] + f * cG1[reg]) * A0;
                    mp[64 + 3 * w]     = (cV[0][0][reg] + f * cV[0][1][reg]) * A1;
                    mp[64 + 3 * w + 1] = (cV[1][0][reg] + f * cV[1][1][reg]) * A1;
                    mp[64 + 3 * w + 2] = (cV[2][0][reg] + f * cV[2][1][reg]) * A1;
                }
            }
            #undef LOADA
            er0 = nr0; er1 = nr1; er2 = nr2; er3 = nr3;
        }
    }

    gbar(&bar[1], GRID);   // msg visible device-wide

    // ============ PHASE C: node gather + epilogue (8 nodes/block) ===========
    {
        const int n0 = vb * 8;
        const float IM = 0.1767766953f;
#pragma unroll
        for (int it = 0; it < 5; ++it) {
            int task = tid + it * 256;
            int nl = task / 160;
            int c = task - nl * 160;
            int n = n0 + nl;
            if (n < N) {
                int cd = cntD[n];
                int cc = cd < DCAP ? cd : DCAP;
                const int* sp = sortedD + n * DCAP;
                float s = 0.f;
                for (int i0 = 0; i0 < cc; i0 += 8) {
                    int4 ia = *(const int4*)(sp + i0);
                    int4 ib = *(const int4*)(sp + i0 + 4);
                    int id[8] = { ia.x, ia.y, ia.z, ia.w, ib.x, ib.y, ib.z, ib.w };
                    float p[8];
#pragma unroll
                    for (int k = 0; k < 8; ++k)
                        p[k] = (i0 + k < cc) ? msg[(size_t)id[k] * 160 + c] : 0.f;
#pragma unroll
                    for (int k = 0; k < 8; ++k) s += p[k];
                }
                sh.ms[nl][c] = s / fmaxf((float)cd, 1.f);
            }
        }
        __syncthreads();

#pragma unroll
        for (int it = 0; it < 2; ++it) {
            int task = tid + it * 256;
            int nl = task >> 6, colp = task & 63;
            int n = n0 + nl;
            if (n >= N) continue;
            const float* m  = sh.ms[nl];
            const float* xp = x + (size_t)n * 128;
            if (colp < 32) {
                int w = colp;
                float mval = m[w];
                float gs = mval * sigmoidf_(mval);
                float dot = 0.f;
#pragma unroll 4
                for (int u = 0; u < 32; ++u) dot += xp[u] * Wss[u * 32 + w];
                float hs = gs + dot * IM;
                out[(size_t)n * 64 + w] = sqrtf(hs * hs + 1e-12f);
            } else {
                int w = colp - 32;
                float gate = sigmoidf_(m[32 + w]);
                float g0 = m[64 + 3 * w + 0] * gate;
                float g1 = m[64 + 3 * w + 1] * gate;
                float g2 = m[64 + 3 * w + 2] * gate;
                float d0 = 0.f, d1 = 0.f, d2 = 0.f;
#pragma unroll 4
                for (int u = 0; u < 32; ++u) {
                    float wvv = Wsv[u * 32 + w];
                    d0 += xp[32 + 3 * u + 0] * wvv;
                    d1 += xp[32 + 3 * u + 1] * wvv;
                    d2 += xp[32 + 3 * u + 2] * wvv;
                }
                float h0 = g0 + d0 * IM, h1 = g1 + d1 * IM, h2 = g2 + d2 * IM;
                out[(size_t)n * 64 + 32 + w] = sqrtf(h0 * h0 + h1 * h1 + h2 * h2 + 1e-12f);
            }
        }
    }
}

extern "C" void kernel_launch(void* const* d_in, const int* in_sizes, int n_in,
                              void* d_out, int out_size, void* d_ws, size_t ws_size,
                              hipStream_t stream)
{
    const float* x    = (const float*)d_in[0];
    const float* ea   = (const float*)d_in[1];
    const float* elen = (const float*)d_in[2];
    const int*   esrc = (const int*)d_in[3];
    const int*   edst = (const int*)d_in[4];
    const float* W1   = (const float*)d_in[5];
    const float* W2   = (const float*)d_in[6];
    const float* Wss  = (const float*)d_in[7];
    const float* Wsv  = (const float*)d_in[8];
    float* out = (float*)d_out;

    const int N = in_sizes[0] / 128;   // 4096
    const int E = in_sizes[2];         // 32768

    float* Bpkf   = (float*)d_ws;                       // 256*28*64 uint4 (7.3 MB)
    float* msg    = Bpkf + (size_t)256 * 28 * 64 * 4;   // 256*BCAP*160 floats (42 MB)
    float* erec   = msg + (size_t)256 * BCAP * 160;     // 256*BCAP*16 floats (4 MB)
    int*   cntL   = (int*)(erec + (size_t)256 * BCAP * 16); // 256
    int*   cntD   = cntL + 256;                         // N
    int*   bar    = cntD + N;                           // 2 barrier counters
    int*   sortedD= bar + 2;                            // N*DCAP
    uint4* Bpk    = (uint4*)Bpkf;

    // zero cntL + cntD + barrier counters in one memset
    hipMemsetAsync(cntL, 0, (size_t)(256 + N + 2) * sizeof(int), stream);

    mega_kernel<<<GRID, 256, 0, stream>>>(x, ea, elen, esrc, edst, W1, W2, Wss, Wsv,
                                          out, Bpk, msg, erec, cntL, cntD, sortedD,
                                          bar, N, E);
}

// Round 11
// 139.589 us; speedup vs baseline: 1.7343x; 1.7343x over previous
//
#include <hip/hip_runtime.h>

#define NIVL  256
#define KINV  51.2f        // 256/5
#define KSTEP 0.01953125f  // 5/256 (exact in fp32)
#define TPW   7168
#define BCAP  256          // max edges per L-bin (avg 128)
#define DCAP  64           // max edges per dst node (avg 8)
#define NROW  11           // distinct t-rows
#define TPACK 448          // T-build+pack blocks: 64 k-groups x 7 w-slices

typedef __attribute__((ext_vector_type(8))) __bf16 bf16x8;
typedef __attribute__((ext_vector_type(4))) float f32x4;
union FragU { uint4 u; bf16x8 v; };

__device__ __forceinline__ float sigmoidf_(float v) { return 1.f / (1.f + expf(-v)); }
__device__ __forceinline__ unsigned bf16r_(float x) { return (__float_as_uint(x) + 0x8000u) >> 16; }
__device__ __forceinline__ unsigned pk_(float lo, float hi) { return (bf16r_(hi) << 16) | bf16r_(lo); }

__device__ __forceinline__ f32x4 mfma_(bf16x8 a, bf16x8 b, f32x4 c) {
    return __builtin_amdgcn_mfma_f32_16x16x32_bf16(a, b, c, 0, 0, 0);
}

// ---- prep: blocks 0..447 fused T-build(5 knots in LDS)+pack -> Bpk;
//      blocks 448.. edge scatter -> erec/cntL/cntD/sortedD(slots). (R8 verbatim)
__global__ __launch_bounds__(256)
void prep_kernel(const float* __restrict__ W1, const float* __restrict__ W2,
                 const float* __restrict__ elen, const int* __restrict__ esrc,
                 const int* __restrict__ edst, const float* __restrict__ ea,
                 uint4* __restrict__ Bpk, int* __restrict__ cntL, int* __restrict__ cntD,
                 float* __restrict__ erec, int* __restrict__ sortedD, int E)
{
    __shared__ float hk_s[5][64];
    __shared__ float Tsl[5][1024];
    const int tid = threadIdx.x;
    const int vb = blockIdx.x;
    if (vb < TPACK) {
        const int bx = vb % 7;
        const int k0 = (vb / 7) * 4;
        for (int idx = tid; idx < 320; idx += 256) {
            int kk = idx >> 6, c = idx & 63;
            float L = (float)(k0 + kk) * KSTEP;
            float d = 0.f;
#pragma unroll
            for (int r = 0; r < 8; ++r) {
                float dd = L - (float)r * (5.f / 7.f);
                d += expf(-dd * dd * 0.98f) * W1[r * 64 + c];
            }
            d *= 0.3535533906f;
            hk_s[kk][c] = d * sigmoidf_(d) * 0.125f;
        }
        __syncthreads();
        float4 acc[5];
#pragma unroll
        for (int q = 0; q < 5; ++q) acc[q] = make_float4(0.f, 0.f, 0.f, 0.f);
        const int pw = bx * 1024 + tid * 4;
#pragma unroll 4
        for (int c = 0; c < 64; ++c) {
            float4 w4 = *(const float4*)(W2 + (size_t)c * TPW + pw);
#pragma unroll
            for (int q = 0; q < 5; ++q) {
                float hv = hk_s[q][c];
                acc[q].x = fmaf(hv, w4.x, acc[q].x);
                acc[q].y = fmaf(hv, w4.y, acc[q].y);
                acc[q].z = fmaf(hv, w4.z, acc[q].z);
                acc[q].w = fmaf(hv, w4.w, acc[q].w);
            }
        }
        __syncthreads();
#pragma unroll
        for (int q = 0; q < 5; ++q)
            *(float4*)&Tsl[q][tid * 4] = acc[q];
        __syncthreads();
        const int lane_s = tid & 63, whs = (tid >> 6) & 1, ih = tid >> 7;
        const int u0p = (lane_s >> 4) * 8, wp = whs * 16 + (lane_s & 15);
#pragma unroll
        for (int t2 = 0; t2 < 2; ++t2) {
            const int jj = k0 + ih + t2 * 2;
            const int kk = jj - k0;
            unsigned ta[4], dd[4];
#pragma unroll
            for (int q = 0; q < 4; ++q) {
                float a0 = Tsl[kk][(u0p + 2 * q) * 32 + wp];
                float a1 = Tsl[kk][(u0p + 2 * q + 1) * 32 + wp];
                float b0 = Tsl[kk + 1][(u0p + 2 * q) * 32 + wp];
                float b1 = Tsl[kk + 1][(u0p + 2 * q + 1) * 32 + wp];
                ta[q] = pk_(a0, a1);
                dd[q] = pk_(b0 - a0, b1 - a1);
            }
            Bpk[((size_t)jj * 28 + bx * 4 + whs) * 64 + lane_s]     = make_uint4(ta[0], ta[1], ta[2], ta[3]);
            Bpk[((size_t)jj * 28 + bx * 4 + 2 + whs) * 64 + lane_s] = make_uint4(dd[0], dd[1], dd[2], dd[3]);
        }
    } else {
        const float I3 = 0.5773502692f, I5 = 0.4472135955f, S2 = 0.7071067812f;
        const float I6 = 0.4082482905f, T6 = 0.8164965809f;
        int e = (vb - TPACK) * 256 + tid;
        if (e < E) {
            float t = elen[e] * KINV;
            int j = (int)t; j = j > 255 ? 255 : j;
            int pos = atomicAdd(&cntL[j], 1);
            if (pos < BCAP) {
                const float* y = ea + (size_t)e * 9;
                float y0 = y[0];
                float a = y[4], b = y[5], c = y[6], d2 = y[7], ee = y[8];
                float4 r0, r1, r2, r3;
                r0.x = t - (float)j;
                r0.y = __int_as_float(esrc[e]);
                r0.z = 0.f;
                r0.w = y0;
                r1.x = y0 * I3;
                r1.y = y[1] * I3; r1.z = y[2] * I3; r1.w = y[3] * I3;
                r2.x = (-c * I6 + ee * S2) * I5;   // M0
                r2.y = a * S2 * I5;                // M1 (=M3)
                r2.z = d2 * S2 * I5;               // M2 (=M6)
                r2.w = (-c * I6 - ee * S2) * I5;   // M4
                r3.x = b * S2 * I5;                // M5 (=M7)
                r3.y = c * T6 * I5;                // M8
                r3.z = 0.f; r3.w = 0.f;
                float4* dst = (float4*)(erec + ((size_t)j * BCAP + pos) * 16);
                dst[0] = r0; dst[1] = r1; dst[2] = r2; dst[3] = r3;
            }
            int slot = j * BCAP + (pos < BCAP ? pos : BCAP - 1);
            int d = edst[e];
            int pd = atomicAdd(&cntD[d], 1);
            if (pd < DCAP) sortedD[d * DCAP + pd] = slot;
        }
    }
}

// ---- main fold: single-wave blocks, NO LDS, NO barriers ----
// Lane l computes edge l&15, u-range (l>>4)*8..+7 -- exactly the MFMA
// A-fragment layout (A[m=l&15][k=(l>>4)*8..]), so t-rows pack lane-locally
// into MFMA operands. 52 MFMAs/chunk (wh=0,1 sequential halves). f crosses
// lanes via __shfl (edge e's record is in lane e). 2048 blocks (8/bin,
// 16-edge chunks) = one full residency round; waves pipeline independently.
__global__ __launch_bounds__(64, 2)
void fold_kernel(const float* __restrict__ x, const int* __restrict__ cntL,
                 const float* __restrict__ erec, const uint4* __restrict__ Bpk,
                 float* __restrict__ msg)
{
    const int j = blockIdx.x >> 3, off = blockIdx.x & 7;
    const int lane = threadIdx.x;
    const int em = lane & 15;        // edge within chunk
    const int quad = lane >> 4;      // u-group of 8
    const int u0 = quad * 8;

    const int cnt = min(cntL[j], BCAP);
    const int nchunk = (cnt + 15) >> 4;
    if (off >= nchunk) return;

    // B-fragments: 28 coalesced b128 loads (both halves, loop-invariant)
    bf16x8 Bt[7][2][2];   // [path][ta/d][wh]
    {
        const uint4* bp = Bpk + (size_t)j * 28 * 64 + lane;
#pragma unroll
        for (int pl = 0; pl < 7; ++pl) {
#pragma unroll
            for (int wh = 0; wh < 2; ++wh) {
                FragU fa; fa.u = bp[(pl * 4 + wh) * 64];     Bt[pl][0][wh] = fa.v;
                FragU fd; fd.u = bp[(pl * 4 + 2 + wh) * 64]; Bt[pl][1][wh] = fd.v;
            }
        }
    }

    const float A0 = 0.125f, A1 = 0.1767766953f;

    for (int ci = off; ci < nchunk; ci += 8) {
        const int base = ci << 4;
        const int cntE = min(16, cnt - base);

        // edge record (4 lanes per edge load the same 64B -- L1 broadcast)
        float4 er0 = {0,0,0,0}, er1 = {0,0,0,0}, er2 = {0,0,0,0}, er3 = {0,0,0,0};
        if (em < cntE) {
            const float4* rp = (const float4*)(erec + ((size_t)j * BCAP + base + em) * 16);
            er0 = rp[0]; er1 = rp[1]; er2 = rp[2]; er3 = rp[3];
        }

        // x row: 8 s-floats + 24 v-floats for this lane's u-range
        float s8[8], vv[24];
        if (em < cntE) {
            int src = __float_as_int(er0.y);
            const float* xp = x + (size_t)src * 128;
            *(float4*)(s8)     = *(const float4*)(xp + u0);
            *(float4*)(s8 + 4) = *(const float4*)(xp + u0 + 4);
#pragma unroll
            for (int q = 0; q < 6; ++q)
                *(float4*)(vv + 4 * q) = *(const float4*)(xp + 32 + 3 * u0 + 4 * q);
        }

        // build 11 t-rows lane-locally, pack straight into MFMA A-frags
        bf16x8 pa[NROW];
        {
            float y0 = er0.w;
            float y0i = er1.x, y1i0 = er1.y, y1i1 = er1.z, y1i2 = er1.w;
            float M0 = er2.x, M1 = er2.y, M2 = er2.z, M4 = er2.w;
            float M5 = er3.x, M8 = er3.y;
            float rv[NROW][8];
            if (em < cntE) {
#pragma unroll
                for (int up = 0; up < 8; ++up) {
                    float s = s8[up];
                    float v0 = vv[3 * up], v1 = vv[3 * up + 1], v2 = vv[3 * up + 2];
                    rv[0][up] = s * y0;
                    rv[1][up] = v0 * y1i0 + v1 * y1i1 + v2 * y1i2;
                    rv[2][up] = s * y1i0;
                    rv[3][up] = s * y1i1;
                    rv[4][up] = s * y1i2;
                    rv[5][up] = v0 * y0i;
                    rv[6][up] = v1 * y0i;
                    rv[7][up] = v2 * y0i;
                    rv[8][up]  = v0 * M0 + v1 * M1 + v2 * M2;
                    rv[9][up]  = v0 * M1 + v1 * M4 + v2 * M5;
                    rv[10][up] = v0 * M2 + v1 * M5 + v2 * M8;
                }
            } else {
#pragma unroll
                for (int r = 0; r < NROW; ++r)
#pragma unroll
                    for (int up = 0; up < 8; ++up) rv[r][up] = 0.f;
            }
#pragma unroll
            for (int r = 0; r < NROW; ++r) {
                FragU f;
                f.u = make_uint4(pk_(rv[r][0], rv[r][1]), pk_(rv[r][2], rv[r][3]),
                                 pk_(rv[r][4], rv[r][5]), pk_(rv[r][6], rv[r][7]));
                pa[r] = f.v;
            }
        }

        const float fr = er0.x;           // frac for this lane's edge
        const int sbase = j * BCAP + base;

        // two output halves sequentially (halves acc pressure)
#pragma unroll
        for (int wh = 0; wh < 2; ++wh) {
            f32x4 cS0 = {0,0,0,0}, cS1 = {0,0,0,0}, cG0 = {0,0,0,0}, cG1 = {0,0,0,0};
            f32x4 cV[3][2];
#pragma unroll
            for (int k = 0; k < 3; ++k) { cV[k][0] = (f32x4){0,0,0,0}; cV[k][1] = (f32x4){0,0,0,0}; }

            cS0 = mfma_(pa[0], Bt[0][0][wh], cS0); cS0 = mfma_(pa[1], Bt[1][0][wh], cS0);
            cS1 = mfma_(pa[0], Bt[0][1][wh], cS1); cS1 = mfma_(pa[1], Bt[1][1][wh], cS1);
            cG0 = mfma_(pa[0], Bt[2][0][wh], cG0); cG0 = mfma_(pa[1], Bt[3][0][wh], cG0);
            cG1 = mfma_(pa[0], Bt[2][1][wh], cG1); cG1 = mfma_(pa[1], Bt[3][1][wh], cG1);
#pragma unroll
            for (int k = 0; k < 3; ++k) {
                cV[k][0] = mfma_(pa[2 + k], Bt[4][0][wh], cV[k][0]);
                cV[k][1] = mfma_(pa[2 + k], Bt[4][1][wh], cV[k][1]);
                cV[k][0] = mfma_(pa[5 + k], Bt[5][0][wh], cV[k][0]);
                cV[k][1] = mfma_(pa[5 + k], Bt[5][1][wh], cV[k][1]);
                cV[k][0] = mfma_(pa[8 + k], Bt[6][0][wh], cV[k][0]);
                cV[k][1] = mfma_(pa[8 + k], Bt[6][1][wh], cV[k][1]);
            }

            const int w = wh * 16 + em;
#pragma unroll
            for (int reg = 0; reg < 4; ++reg) {
                int e = quad * 4 + reg;
                float f = __shfl(fr, e);   // lane e holds edge e's record
                if (e < cntE) {
                    float* mp = msg + (size_t)(sbase + e) * 160;
                    mp[w]            = (cS0[reg] + f * cS1[reg]) * A0;
                    mp[32 + w]       = (cG0[reg] + f * cG1[reg]) * A0;
                    mp[64 + 3 * w]     = (cV[0][0][reg] + f * cV[0][1][reg]) * A1;
                    mp[64 + 3 * w + 1] = (cV[1][0][reg] + f * cV[1][1][reg]) * A1;
                    mp[64 + 3 * w + 2] = (cV[2][0][reg] + f * cV[2][1][reg]) * A1;
                }
            }
        }
    }
}

// ---- fused gather + node epilogue: 8 nodes per block (R8 verbatim) ----
__global__ __launch_bounds__(256)
void node_kernel(const float* __restrict__ x, const float* __restrict__ Wss,
                 const float* __restrict__ Wsv, const float* __restrict__ msg,
                 const int* __restrict__ sortedD, const int* __restrict__ cntD,
                 float* __restrict__ out, int N)
{
    __shared__ float ms[8][160];
    const int tid = threadIdx.x;
    const int n0 = blockIdx.x * 8;
    const float IM = 0.1767766953f;  // 1/sqrt(32)

#pragma unroll
    for (int it = 0; it < 5; ++it) {
        int task = tid + it * 256;
        int nl = task / 160;
        int c = task - nl * 160;
        int n = n0 + nl;
        if (n < N) {
            int cd = cntD[n];
            int cc = cd < DCAP ? cd : DCAP;
            const int* sp = sortedD + n * DCAP;
            float s = 0.f;
            for (int i0 = 0; i0 < cc; i0 += 8) {
                int4 ia = *(const int4*)(sp + i0);
                int4 ib = *(const int4*)(sp + i0 + 4);
                int id[8] = { ia.x, ia.y, ia.z, ia.w, ib.x, ib.y, ib.z, ib.w };
                float p[8];
#pragma unroll
                for (int k = 0; k < 8; ++k)
                    p[k] = (i0 + k < cc) ? msg[(size_t)id[k] * 160 + c] : 0.f;
#pragma unroll
                for (int k = 0; k < 8; ++k) s += p[k];
            }
            ms[nl][c] = s / fmaxf((float)cd, 1.f);
        }
    }
    __syncthreads();

#pragma unroll
    for (int it = 0; it < 2; ++it) {
        int task = tid + it * 256;
        int nl = task >> 6, col = task & 63;
        int n = n0 + nl;
        if (n >= N) continue;
        const float* m  = ms[nl];
        const float* xp = x + (size_t)n * 128;
        if (col < 32) {
            int w = col;
            float mval = m[w];
            float gs = mval * sigmoidf_(mval);
            float dot = 0.f;
#pragma unroll 4
            for (int u = 0; u < 32; ++u) dot += xp[u] * Wss[u * 32 + w];
            float hs = gs + dot * IM;
            out[(size_t)n * 64 + w] = sqrtf(hs * hs + 1e-12f);
        } else {
            int w = col - 32;
            float gate = sigmoidf_(m[32 + w]);
            float g0 = m[64 + 3 * w + 0] * gate;
            float g1 = m[64 + 3 * w + 1] * gate;
            float g2 = m[64 + 3 * w + 2] * gate;
            float d0 = 0.f, d1 = 0.f, d2 = 0.f;
#pragma unroll 4
            for (int u = 0; u < 32; ++u) {
                float wvv = Wsv[u * 32 + w];
                d0 += xp[32 + 3 * u + 0] * wvv;
                d1 += xp[32 + 3 * u + 1] * wvv;
                d2 += xp[32 + 3 * u + 2] * wvv;
            }
            float h0 = g0 + d0 * IM, h1 = g1 + d1 * IM, h2 = g2 + d2 * IM;
            out[(size_t)n * 64 + 32 + w] = sqrtf(h0 * h0 + h1 * h1 + h2 * h2 + 1e-12f);
        }
    }
}

extern "C" void kernel_launch(void* const* d_in, const int* in_sizes, int n_in,
                              void* d_out, int out_size, void* d_ws, size_t ws_size,
                              hipStream_t stream)
{
    const float* x    = (const float*)d_in[0];
    const float* ea   = (const float*)d_in[1];
    const float* elen = (const float*)d_in[2];
    const int*   esrc = (const int*)d_in[3];
    const int*   edst = (const int*)d_in[4];
    const float* W1   = (const float*)d_in[5];
    const float* W2   = (const float*)d_in[6];
    const float* Wss  = (const float*)d_in[7];
    const float* Wsv  = (const float*)d_in[8];
    float* out = (float*)d_out;

    const int N = in_sizes[0] / 128;   // 4096
    const int E = in_sizes[2];         // 32768

    float* Bpkf   = (float*)d_ws;                       // 256*28*64 uint4 (7.3 MB)
    float* msg    = Bpkf + (size_t)256 * 28 * 64 * 4;   // 256*BCAP*160 floats (42 MB)
    float* erec   = msg + (size_t)256 * BCAP * 160;     // 256*BCAP*16 floats (4 MB)
    int*   cntL   = (int*)(erec + (size_t)256 * BCAP * 16); // 256
    int*   cntD   = cntL + 256;                         // N
    int*   sortedD= cntD + N;                           // N*DCAP
    uint4* Bpk    = (uint4*)Bpkf;

    hipMemsetAsync(cntL, 0, (size_t)(256 + N) * sizeof(int), stream);

    prep_kernel<<<TPACK + (E + 255) / 256, 256, 0, stream>>>(W1, W2, elen, esrc, edst, ea, Bpk, cntL, cntD, erec, sortedD, E);
    fold_kernel<<<NIVL * 8, 64, 0, stream>>>(x, cntL, erec, Bpk, msg);
    node_kernel<<<(N + 7) / 8, 256, 0, stream>>>(x, Wss, Wsv, msg, sortedD, cntD, out, N);
}

// Round 12
// 138.595 us; speedup vs baseline: 1.7467x; 1.0072x over previous
//
#include <hip/hip_runtime.h>

#define NIVL  256
#define KINV  51.2f        // 256/5
#define KSTEP 0.01953125f  // 5/256 (exact in fp32)
#define TPW   7168
#define BCAP  256          // max edges per L-bin (avg 128)
#define DCAP  64           // max edges per dst node (avg 8)
#define NROW  11           // distinct t-rows
#define TSTR  40           // u-stride (pad 32->40)
#define TPACK 448          // T-build+pack blocks: 64 k-groups x 7 w-slices

typedef __attribute__((ext_vector_type(8))) __bf16 bf16x8;
typedef __attribute__((ext_vector_type(4))) float f32x4;
union FragU { uint4 u; bf16x8 v; };

__device__ __forceinline__ float sigmoidf_(float v) { return 1.f / (1.f + expf(-v)); }
__device__ __forceinline__ unsigned bf16r_(float x) { return (__float_as_uint(x) + 0x8000u) >> 16; }
__device__ __forceinline__ unsigned pk_(float lo, float hi) { return (bf16r_(hi) << 16) | bf16r_(lo); }
__device__ __forceinline__ float b2f_(unsigned short u) { return __uint_as_float((unsigned)u << 16); }

__device__ __forceinline__ f32x4 mfma_(bf16x8 a, bf16x8 b, f32x4 c) {
    return __builtin_amdgcn_mfma_f32_16x16x32_bf16(a, b, c, 0, 0, 0);
}

// ---- prep: blocks 0..447 fused T-build(5 knots in LDS)+pack -> Bpk;
//      blocks 448.. edge scatter -> erec/cntL/cntD/sortedD(slots). (R8 verbatim)
__global__ __launch_bounds__(256)
void prep_kernel(const float* __restrict__ W1, const float* __restrict__ W2,
                 const float* __restrict__ elen, const int* __restrict__ esrc,
                 const int* __restrict__ edst, const float* __restrict__ ea,
                 uint4* __restrict__ Bpk, int* __restrict__ cntL, int* __restrict__ cntD,
                 float* __restrict__ erec, int* __restrict__ sortedD, int E)
{
    __shared__ float hk_s[5][64];
    __shared__ float Tsl[5][1024];
    const int tid = threadIdx.x;
    const int vb = blockIdx.x;
    if (vb < TPACK) {
        const int bx = vb % 7;
        const int k0 = (vb / 7) * 4;
        for (int idx = tid; idx < 320; idx += 256) {
            int kk = idx >> 6, c = idx & 63;
            float L = (float)(k0 + kk) * KSTEP;
            float d = 0.f;
#pragma unroll
            for (int r = 0; r < 8; ++r) {
                float dd = L - (float)r * (5.f / 7.f);
                d += expf(-dd * dd * 0.98f) * W1[r * 64 + c];
            }
            d *= 0.3535533906f;
            hk_s[kk][c] = d * sigmoidf_(d) * 0.125f;
        }
        __syncthreads();
        float4 acc[5];
#pragma unroll
        for (int q = 0; q < 5; ++q) acc[q] = make_float4(0.f, 0.f, 0.f, 0.f);
        const int pw = bx * 1024 + tid * 4;
#pragma unroll 4
        for (int c = 0; c < 64; ++c) {
            float4 w4 = *(const float4*)(W2 + (size_t)c * TPW + pw);
#pragma unroll
            for (int q = 0; q < 5; ++q) {
                float hv = hk_s[q][c];
                acc[q].x = fmaf(hv, w4.x, acc[q].x);
                acc[q].y = fmaf(hv, w4.y, acc[q].y);
                acc[q].z = fmaf(hv, w4.z, acc[q].z);
                acc[q].w = fmaf(hv, w4.w, acc[q].w);
            }
        }
        __syncthreads();
#pragma unroll
        for (int q = 0; q < 5; ++q)
            *(float4*)&Tsl[q][tid * 4] = acc[q];
        __syncthreads();
        const int lane_s = tid & 63, whs = (tid >> 6) & 1, ih = tid >> 7;
        const int u0p = (lane_s >> 4) * 8, wp = whs * 16 + (lane_s & 15);
#pragma unroll
        for (int t2 = 0; t2 < 2; ++t2) {
            const int jj = k0 + ih + t2 * 2;
            const int kk = jj - k0;
            unsigned ta[4], dd[4];
#pragma unroll
            for (int q = 0; q < 4; ++q) {
                float a0 = Tsl[kk][(u0p + 2 * q) * 32 + wp];
                float a1 = Tsl[kk][(u0p + 2 * q + 1) * 32 + wp];
                float b0 = Tsl[kk + 1][(u0p + 2 * q) * 32 + wp];
                float b1 = Tsl[kk + 1][(u0p + 2 * q + 1) * 32 + wp];
                ta[q] = pk_(a0, a1);
                dd[q] = pk_(b0 - a0, b1 - a1);
            }
            Bpk[((size_t)jj * 28 + bx * 4 + whs) * 64 + lane_s]     = make_uint4(ta[0], ta[1], ta[2], ta[3]);
            Bpk[((size_t)jj * 28 + bx * 4 + 2 + whs) * 64 + lane_s] = make_uint4(dd[0], dd[1], dd[2], dd[3]);
        }
    } else {
        const float I3 = 0.5773502692f, I5 = 0.4472135955f, S2 = 0.7071067812f;
        const float I6 = 0.4082482905f, T6 = 0.8164965809f;
        int e = (vb - TPACK) * 256 + tid;
        if (e < E) {
            float t = elen[e] * KINV;
            int j = (int)t; j = j > 255 ? 255 : j;
            int pos = atomicAdd(&cntL[j], 1);
            if (pos < BCAP) {
                const float* y = ea + (size_t)e * 9;
                float y0 = y[0];
                float a = y[4], b = y[5], c = y[6], d2 = y[7], ee = y[8];
                float4 r0, r1, r2, r3;
                r0.x = t - (float)j;
                r0.y = __int_as_float(esrc[e]);
                r0.z = 0.f;
                r0.w = y0;
                r1.x = y0 * I3;
                r1.y = y[1] * I3; r1.z = y[2] * I3; r1.w = y[3] * I3;
                r2.x = (-c * I6 + ee * S2) * I5;   // M0
                r2.y = a * S2 * I5;                // M1 (=M3)
                r2.z = d2 * S2 * I5;               // M2 (=M6)
                r2.w = (-c * I6 - ee * S2) * I5;   // M4
                r3.x = b * S2 * I5;                // M5 (=M7)
                r3.y = c * T6 * I5;                // M8
                r3.z = 0.f; r3.w = 0.f;
                float4* dst = (float4*)(erec + ((size_t)j * BCAP + pos) * 16);
                dst[0] = r0; dst[1] = r1; dst[2] = r2; dst[3] = r3;
            }
            int slot = j * BCAP + (pos < BCAP ? pos : BCAP - 1);
            int d = edst[e];
            int pd = atomicAdd(&cntD[d], 1);
            if (pd < DCAP) sortedD[d * DCAP + pd] = slot;
        }
    }
}

// ---- main fold: R8 structure; msg stored in bf16 (halves write traffic) ----
__global__ __launch_bounds__(256, 2)
void fold_kernel(const float* __restrict__ x, const int* __restrict__ cntL,
                 const float* __restrict__ erec, const uint4* __restrict__ Bpk,
                 unsigned short* __restrict__ msg)
{
    const int j = blockIdx.x >> 1, half = blockIdx.x & 1;
    __shared__ __align__(16) unsigned short TB[2 * NROW * 16 * TSTR]; // 28160 B
    __shared__ float ECF[32];
    const int tid = threadIdx.x;

    const int cnt = min(cntL[j], BCAP);
    const int nchunk = (cnt + 31) >> 5;
    const int te = tid & 31, sub = tid >> 5;
    const int wv = tid >> 6, lane = tid & 63;
    const int sg = wv >> 1, wh = wv & 1;
    const int col = lane & 15, quad = lane >> 4;

    float4 er0 = {0,0,0,0}, er1 = {0,0,0,0}, er2 = {0,0,0,0}, er3 = {0,0,0,0};
    if (half < nchunk) {
        int ce = min(32, cnt - (half << 5));
        if (te < ce) {
            const float4* rp = (const float4*)(erec + ((size_t)j * BCAP + (half << 5) + te) * 16);
            er0 = rp[0]; er1 = rp[1]; er2 = rp[2]; er3 = rp[3];
        }
    }

    bf16x8 Bt[7][2];
    {
        const uint4* bp = Bpk + (size_t)j * 28 * 64 + lane;
#pragma unroll
        for (int pl = 0; pl < 7; ++pl) {
            FragU fa; fa.u = bp[(pl * 4 + wh) * 64];     Bt[pl][0] = fa.v;
            FragU fd; fd.u = bp[(pl * 4 + 2 + wh) * 64]; Bt[pl][1] = fd.v;
        }
    }

    const float A0 = 0.125f, A1 = 0.1767766953f;

    for (int ci = half; ci < nchunk; ci += 2) {
        const int base = ci << 5;
        const int cntE = min(32, cnt - base);

        const int u0 = sub * 4;
        float s4[4], vvx[12];
        if (te < cntE) {
            int src = __float_as_int(er0.y);
            const float* xp = x + (size_t)src * 128;
            *(float4*)s4 = *(const float4*)(xp + u0);
            *(float4*)(vvx)     = *(const float4*)(xp + 32 + 3 * u0);
            *(float4*)(vvx + 4) = *(const float4*)(xp + 32 + 3 * u0 + 4);
            *(float4*)(vvx + 8) = *(const float4*)(xp + 32 + 3 * u0 + 8);
        }
        float4 nr0 = {0,0,0,0}, nr1 = {0,0,0,0}, nr2 = {0,0,0,0}, nr3 = {0,0,0,0};
        const int cin = ci + 2;
        if (cin < nchunk) {
            int ce2 = min(32, cnt - (cin << 5));
            if (te < ce2) {
                const float4* rp = (const float4*)(erec + ((size_t)j * BCAP + (cin << 5) + te) * 16);
                nr0 = rp[0]; nr1 = rp[1]; nr2 = rp[2]; nr3 = rp[3];
            }
        }

        __syncthreads();

        {
            const int esg = te >> 4, e16 = te & 15;
            float rv[NROW][4];
            if (te < cntE) {
                float y0 = er0.w;
                float y0i = er1.x, y1i0 = er1.y, y1i1 = er1.z, y1i2 = er1.w;
                float M0 = er2.x, M1 = er2.y, M2 = er2.z, M4 = er2.w;
                float M5 = er3.x, M8 = er3.y;
                if (sub == 0) ECF[te] = er0.x;
#pragma unroll
                for (int up = 0; up < 4; ++up) {
                    float s = s4[up];
                    float v0 = vvx[3 * up], v1 = vvx[3 * up + 1], v2 = vvx[3 * up + 2];
                    rv[0][up] = s * y0;
                    rv[1][up] = v0 * y1i0 + v1 * y1i1 + v2 * y1i2;
                    rv[2][up] = s * y1i0;
                    rv[3][up] = s * y1i1;
                    rv[4][up] = s * y1i2;
                    rv[5][up] = v0 * y0i;
                    rv[6][up] = v1 * y0i;
                    rv[7][up] = v2 * y0i;
                    rv[8][up]  = v0 * M0 + v1 * M1 + v2 * M2;
                    rv[9][up]  = v0 * M1 + v1 * M4 + v2 * M5;
                    rv[10][up] = v0 * M2 + v1 * M5 + v2 * M8;
                }
            } else {
#pragma unroll
                for (int r = 0; r < NROW; ++r)
#pragma unroll
                    for (int up = 0; up < 4; ++up) rv[r][up] = 0.f;
            }
#pragma unroll
            for (int r = 0; r < NROW; ++r) {
                unsigned lo = pk_(rv[r][0], rv[r][1]);
                unsigned hi = pk_(rv[r][2], rv[r][3]);
                *(uint2*)&TB[((esg * NROW + r) * 16 + e16) * TSTR + u0] = make_uint2(lo, hi);
            }
        }
        __syncthreads();

        f32x4 cS0 = {0,0,0,0}, cS1 = {0,0,0,0}, cG0 = {0,0,0,0}, cG1 = {0,0,0,0};
        f32x4 cV[3][2];
#pragma unroll
        for (int k = 0; k < 3; ++k) { cV[k][0] = (f32x4){0,0,0,0}; cV[k][1] = (f32x4){0,0,0,0}; }

        #define LOADA(r) ({ FragU fa_; fa_.u = *(const uint4*)&TB[((sg * NROW + (r)) * 16 + col) * TSTR + quad * 8]; fa_.v; })

        bf16x8 a0 = LOADA(0), a1 = LOADA(1);
        cS0 = mfma_(a0, Bt[0][0], cS0); cS0 = mfma_(a1, Bt[1][0], cS0);
        cS1 = mfma_(a0, Bt[0][1], cS1); cS1 = mfma_(a1, Bt[1][1], cS1);
        cG0 = mfma_(a0, Bt[2][0], cG0); cG0 = mfma_(a1, Bt[3][0], cG0);
        cG1 = mfma_(a0, Bt[2][1], cG1); cG1 = mfma_(a1, Bt[3][1], cG1);
#pragma unroll
        for (int k = 0; k < 3; ++k) {
            bf16x8 ak;
            ak = LOADA(2 + k);
            cV[k][0] = mfma_(ak, Bt[4][0], cV[k][0]);
            cV[k][1] = mfma_(ak, Bt[4][1], cV[k][1]);
            ak = LOADA(5 + k);
            cV[k][0] = mfma_(ak, Bt[5][0], cV[k][0]);
            cV[k][1] = mfma_(ak, Bt[5][1], cV[k][1]);
            ak = LOADA(8 + k);
            cV[k][0] = mfma_(ak, Bt[6][0], cV[k][0]);
            cV[k][1] = mfma_(ak, Bt[6][1], cV[k][1]);
        }

        // epilogue: combine Ta + f*D, scale, store bf16 to slot-contiguous rows
        const int w = wh * 16 + col;
        const int sbase = j * BCAP + base;
#pragma unroll
        for (int reg = 0; reg < 4; ++reg) {
            int e = sg * 16 + quad * 4 + reg;
            if (e < cntE) {
                float f = ECF[e];
                unsigned short* mp = msg + (size_t)(sbase + e) * 160;
                mp[w]            = (unsigned short)bf16r_((cS0[reg] + f * cS1[reg]) * A0);
                mp[32 + w]       = (unsigned short)bf16r_((cG0[reg] + f * cG1[reg]) * A0);
                mp[64 + 3 * w]     = (unsigned short)bf16r_((cV[0][0][reg] + f * cV[0][1][reg]) * A1);
                mp[64 + 3 * w + 1] = (unsigned short)bf16r_((cV[1][0][reg] + f * cV[1][1][reg]) * A1);
                mp[64 + 3 * w + 2] = (unsigned short)bf16r_((cV[2][0][reg] + f * cV[2][1][reg]) * A1);
            }
        }
        #undef LOADA
        er0 = nr0; er1 = nr1; er2 = nr2; er3 = nr3;
    }
}

// ---- fused gather + node epilogue: 8 nodes/block; bf16 msg gather ----
__global__ __launch_bounds__(256)
void node_kernel(const float* __restrict__ x, const float* __restrict__ Wss,
                 const float* __restrict__ Wsv, const unsigned short* __restrict__ msg,
                 const int* __restrict__ sortedD, const int* __restrict__ cntD,
                 float* __restrict__ out, int N)
{
    __shared__ float ms[8][160];
    const int tid = threadIdx.x;
    const int n0 = blockIdx.x * 8;
    const float IM = 0.1767766953f;  // 1/sqrt(32)

#pragma unroll
    for (int it = 0; it < 5; ++it) {
        int task = tid + it * 256;
        int nl = task / 160;
        int c = task - nl * 160;
        int n = n0 + nl;
        if (n < N) {
            int cd = cntD[n];
            int cc = cd < DCAP ? cd : DCAP;
            const int* sp = sortedD + n * DCAP;
            float s = 0.f;
            for (int i0 = 0; i0 < cc; i0 += 8) {
                int4 ia = *(const int4*)(sp + i0);
                int4 ib = *(const int4*)(sp + i0 + 4);
                int id[8] = { ia.x, ia.y, ia.z, ia.w, ib.x, ib.y, ib.z, ib.w };
                float p[8];
#pragma unroll
                for (int k = 0; k < 8; ++k)
                    p[k] = (i0 + k < cc) ? b2f_(msg[(size_t)id[k] * 160 + c]) : 0.f;
#pragma unroll
                for (int k = 0; k < 8; ++k) s += p[k];
            }
            ms[nl][c] = s / fmaxf((float)cd, 1.f);
        }
    }
    __syncthreads();

#pragma unroll
    for (int it = 0; it < 2; ++it) {
        int task = tid + it * 256;
        int nl = task >> 6, col = task & 63;
        int n = n0 + nl;
        if (n >= N) continue;
        const float* m  = ms[nl];
        const float* xp = x + (size_t)n * 128;
        if (col < 32) {
            int w = col;
            float mval = m[w];
            float gs = mval * sigmoidf_(mval);
            float dot = 0.f;
#pragma unroll 4
            for (int u = 0; u < 32; ++u) dot += xp[u] * Wss[u * 32 + w];
            float hs = gs + dot * IM;
            out[(size_t)n * 64 + w] = sqrtf(hs * hs + 1e-12f);
        } else {
            int w = col - 32;
            float gate = sigmoidf_(m[32 + w]);
            float g0 = m[64 + 3 * w + 0] * gate;
            float g1 = m[64 + 3 * w + 1] * gate;
            float g2 = m[64 + 3 * w + 2] * gate;
            float d0 = 0.f, d1 = 0.f, d2 = 0.f;
#pragma unroll 4
            for (int u = 0; u < 32; ++u) {
                float wvv = Wsv[u * 32 + w];
                d0 += xp[32 + 3 * u + 0] * wvv;
                d1 += xp[32 + 3 * u + 1] * wvv;
                d2 += xp[32 + 3 * u + 2] * wvv;
            }
            float h0 = g0 + d0 * IM, h1 = g1 + d1 * IM, h2 = g2 + d2 * IM;
            out[(size_t)n * 64 + 32 + w] = sqrtf(h0 * h0 + h1 * h1 + h2 * h2 + 1e-12f);
        }
    }
}

extern "C" void kernel_launch(void* const* d_in, const int* in_sizes, int n_in,
                              void* d_out, int out_size, void* d_ws, size_t ws_size,
                              hipStream_t stream)
{
    const float* x    = (const float*)d_in[0];
    const float* ea   = (const float*)d_in[1];
    const float* elen = (const float*)d_in[2];
    const int*   esrc = (const int*)d_in[3];
    const int*   edst = (const int*)d_in[4];
    const float* W1   = (const float*)d_in[5];
    const float* W2   = (const float*)d_in[6];
    const float* Wss  = (const float*)d_in[7];
    const float* Wsv  = (const float*)d_in[8];
    float* out = (float*)d_out;

    const int N = in_sizes[0] / 128;   // 4096
    const int E = in_sizes[2];         // 32768

    float* Bpkf   = (float*)d_ws;                       // 256*28*64 uint4 (7.3 MB)
    unsigned short* msg = (unsigned short*)(Bpkf + (size_t)256 * 28 * 64 * 4); // 256*BCAP*160 bf16 (21 MB)
    float* erec   = (float*)(msg + (size_t)256 * BCAP * 160);  // 256*BCAP*16 floats (4 MB)
    int*   cntL   = (int*)(erec + (size_t)256 * BCAP * 16);    // 256
    int*   cntD   = cntL + 256;                         // N
    int*   sortedD= cntD + N;                           // N*DCAP
    uint4* Bpk    = (uint4*)Bpkf;

    hipMemsetAsync(cntL, 0, (size_t)(256 + N) * sizeof(int), stream);

    prep_kernel<<<TPACK + (E + 255) / 256, 256, 0, stream>>>(W1, W2, elen, esrc, edst, ea, Bpk, cntL, cntD, erec, sortedD, E);
    fold_kernel<<<NIVL * 2, 256, 0, stream>>>(x, cntL, erec, Bpk, msg);
    node_kernel<<<(N + 7) / 8, 256, 0, stream>>>(x, Wss, Wsv, msg, sortedD, cntD, out, N);
}

// Round 13
// 133.475 us; speedup vs baseline: 1.8137x; 1.0384x over previous
//
#include <hip/hip_runtime.h>

#define NIVL  256
#define KINV  51.2f        // 256/5
#define KSTEP 0.01953125f  // 5/256 (exact in fp32)
#define TPW   7168
#define BCAP  256          // max edges per L-bin (avg 128)
#define DCAP  64           // max edges per dst node (avg 8)
#define NROW  11           // distinct t-rows
#define TSTR  40           // u-stride (pad 32->40)
#define TPACK 448          // T-build+pack blocks: 64 k-groups x 7 w-slices

typedef __attribute__((ext_vector_type(8))) __bf16 bf16x8;
typedef __attribute__((ext_vector_type(4))) float f32x4;
union FragU { uint4 u; bf16x8 v; };

__device__ __forceinline__ float sigmoidf_(float v) { return 1.f / (1.f + expf(-v)); }
__device__ __forceinline__ unsigned bf16r_(float x) { return (__float_as_uint(x) + 0x8000u) >> 16; }
__device__ __forceinline__ unsigned pk_(float lo, float hi) { return (bf16r_(hi) << 16) | bf16r_(lo); }

__device__ __forceinline__ f32x4 mfma_(bf16x8 a, bf16x8 b, f32x4 c) {
    return __builtin_amdgcn_mfma_f32_16x16x32_bf16(a, b, c, 0, 0, 0);
}

// ---- prep: blocks 0..447 fused T-build(5 knots in LDS)+pack -> Bpk;
//      blocks 448.. edge scatter -> erec/cntL/cntD/sortedD(slots).
// T never touches global memory; pack launch eliminated.
__global__ __launch_bounds__(256)
void prep_kernel(const float* __restrict__ W1, const float* __restrict__ W2,
                 const float* __restrict__ elen, const int* __restrict__ esrc,
                 const int* __restrict__ edst, const float* __restrict__ ea,
                 uint4* __restrict__ Bpk, int* __restrict__ cntL, int* __restrict__ cntD,
                 float* __restrict__ erec, int* __restrict__ sortedD, int E)
{
    __shared__ float hk_s[5][64];
    __shared__ float Tsl[5][1024];
    const int tid = threadIdx.x;
    const int vb = blockIdx.x;
    if (vb < TPACK) {
        const int bx = vb % 7;            // W2 slice (1024 cols)
        const int k0 = (vb / 7) * 4;      // first interval of this group
        for (int idx = tid; idx < 320; idx += 256) {
            int kk = idx >> 6, c = idx & 63;
            float L = (float)(k0 + kk) * KSTEP;
            float d = 0.f;
#pragma unroll
            for (int r = 0; r < 8; ++r) {
                float dd = L - (float)r * (5.f / 7.f);
                d += expf(-dd * dd * 0.98f) * W1[r * 64 + c];
            }
            d *= 0.3535533906f;                      // 1/sqrt(8)
            hk_s[kk][c] = d * sigmoidf_(d) * 0.125f; // silu * 1/sqrt(64)
        }
        __syncthreads();
        float4 acc[5];
#pragma unroll
        for (int q = 0; q < 5; ++q) acc[q] = make_float4(0.f, 0.f, 0.f, 0.f);
        const int pw = bx * 1024 + tid * 4;
#pragma unroll 4
        for (int c = 0; c < 64; ++c) {
            float4 w4 = *(const float4*)(W2 + (size_t)c * TPW + pw);
#pragma unroll
            for (int q = 0; q < 5; ++q) {
                float hv = hk_s[q][c];
                acc[q].x = fmaf(hv, w4.x, acc[q].x);
                acc[q].y = fmaf(hv, w4.y, acc[q].y);
                acc[q].z = fmaf(hv, w4.z, acc[q].z);
                acc[q].w = fmaf(hv, w4.w, acc[q].w);
            }
        }
        __syncthreads();
#pragma unroll
        for (int q = 0; q < 5; ++q)
            *(float4*)&Tsl[q][tid * 4] = acc[q];
        __syncthreads();
        // pack 4 intervals of this slice directly from LDS
        const int lane_s = tid & 63, whs = (tid >> 6) & 1, ih = tid >> 7;
        const int u0p = (lane_s >> 4) * 8, wp = whs * 16 + (lane_s & 15);
#pragma unroll
        for (int t2 = 0; t2 < 2; ++t2) {
            const int jj = k0 + ih + t2 * 2;   // interval
            const int kk = jj - k0;            // local knot
            unsigned ta[4], dd[4];
#pragma unroll
            for (int q = 0; q < 4; ++q) {
                float a0 = Tsl[kk][(u0p + 2 * q) * 32 + wp];
                float a1 = Tsl[kk][(u0p + 2 * q + 1) * 32 + wp];
                float b0 = Tsl[kk + 1][(u0p + 2 * q) * 32 + wp];
                float b1 = Tsl[kk + 1][(u0p + 2 * q + 1) * 32 + wp];
                ta[q] = pk_(a0, a1);
                dd[q] = pk_(b0 - a0, b1 - a1);
            }
            Bpk[((size_t)jj * 28 + bx * 4 + whs) * 64 + lane_s]     = make_uint4(ta[0], ta[1], ta[2], ta[3]);
            Bpk[((size_t)jj * 28 + bx * 4 + 2 + whs) * 64 + lane_s] = make_uint4(dd[0], dd[1], dd[2], dd[3]);
        }
    } else {
        const float I3 = 0.5773502692f, I5 = 0.4472135955f, S2 = 0.7071067812f;
        const float I6 = 0.4082482905f, T6 = 0.8164965809f;
        int e = (vb - TPACK) * 256 + tid;
        if (e < E) {
            float t = elen[e] * KINV;
            int j = (int)t; j = j > 255 ? 255 : j;
            int pos = atomicAdd(&cntL[j], 1);
            if (pos < BCAP) {
                const float* y = ea + (size_t)e * 9;
                float y0 = y[0];
                float a = y[4], b = y[5], c = y[6], d2 = y[7], ee = y[8];
                float4 r0, r1, r2, r3;
                r0.x = t - (float)j;
                r0.y = __int_as_float(esrc[e]);
                r0.z = 0.f;                        // (unused; fold derives slot)
                r0.w = y0;
                r1.x = y0 * I3;
                r1.y = y[1] * I3; r1.z = y[2] * I3; r1.w = y[3] * I3;
                r2.x = (-c * I6 + ee * S2) * I5;   // M0
                r2.y = a * S2 * I5;                // M1 (=M3)
                r2.z = d2 * S2 * I5;               // M2 (=M6)
                r2.w = (-c * I6 - ee * S2) * I5;   // M4
                r3.x = b * S2 * I5;                // M5 (=M7)
                r3.y = c * T6 * I5;                // M8
                r3.z = 0.f; r3.w = 0.f;
                float4* dst = (float4*)(erec + ((size_t)j * BCAP + pos) * 16);
                dst[0] = r0; dst[1] = r1; dst[2] = r2; dst[3] = r3;
            }
            // msg is slot-indexed: sortedD stores the bin slot (clamped in-bounds)
            int slot = j * BCAP + (pos < BCAP ? pos : BCAP - 1);
            int d = edst[e];
            int pd = atomicAdd(&cntD[d], 1);
            if (pd < DCAP) sortedD[d * DCAP + pd] = slot;
        }
    }
}

// ---- main fold: MFMA, register B-frags from Bpk, slot-indexed msg stores ----
// 2 blocks per interval (half-strided chunks). msg rows for a chunk's 32 edges
// are contiguous (slot = j*BCAP+base+e) -> block collectively covers full
// cachelines -> no partial-line HBM writes. LDS = TB only; LB(256,2).
__global__ __launch_bounds__(256, 2)
void fold_kernel(const float* __restrict__ x, const int* __restrict__ cntL,
                 const float* __restrict__ erec, const uint4* __restrict__ Bpk,
                 float* __restrict__ msg)
{
    const int j = blockIdx.x >> 1, half = blockIdx.x & 1;
    __shared__ __align__(16) unsigned short TB[2 * NROW * 16 * TSTR]; // 28160 B
    __shared__ float ECF[32];
    const int tid = threadIdx.x;

    const int cnt = min(cntL[j], BCAP);
    const int nchunk = (cnt + 31) >> 5;
    const int te = tid & 31, sub = tid >> 5;
    const int wv = tid >> 6, lane = tid & 63;
    const int sg = wv >> 1, wh = wv & 1;
    const int col = lane & 15, quad = lane >> 4;

    // prologue: first chunk's edge record
    float4 er0 = {0,0,0,0}, er1 = {0,0,0,0}, er2 = {0,0,0,0}, er3 = {0,0,0,0};
    if (half < nchunk) {
        int ce = min(32, cnt - (half << 5));
        if (te < ce) {
            const float4* rp = (const float4*)(erec + ((size_t)j * BCAP + (half << 5) + te) * 16);
            er0 = rp[0]; er1 = rp[1]; er2 = rp[2]; er3 = rp[3];
        }
    }

    // B-fragments: 14 coalesced b128 loads (loop-invariant)
    bf16x8 Bt[7][2];
    {
        const uint4* bp = Bpk + (size_t)j * 28 * 64 + lane;
#pragma unroll
        for (int pl = 0; pl < 7; ++pl) {
            FragU fa; fa.u = bp[(pl * 4 + wh) * 64];     Bt[pl][0] = fa.v;
            FragU fd; fd.u = bp[(pl * 4 + 2 + wh) * 64]; Bt[pl][1] = fd.v;
        }
    }

    const float A0 = 0.125f, A1 = 0.1767766953f;

    for (int ci = half; ci < nchunk; ci += 2) {
        const int base = ci << 5;
        const int cntE = min(32, cnt - base);

        const int u0 = sub * 4;
        float s4[4], vvx[12];
        if (te < cntE) {
            int src = __float_as_int(er0.y);
            const float* xp = x + (size_t)src * 128;
            *(float4*)s4 = *(const float4*)(xp + u0);
            *(float4*)(vvx)     = *(const float4*)(xp + 32 + 3 * u0);
            *(float4*)(vvx + 4) = *(const float4*)(xp + 32 + 3 * u0 + 4);
            *(float4*)(vvx + 8) = *(const float4*)(xp + 32 + 3 * u0 + 8);
        }
        float4 nr0 = {0,0,0,0}, nr1 = {0,0,0,0}, nr2 = {0,0,0,0}, nr3 = {0,0,0,0};
        const int cin = ci + 2;
        if (cin < nchunk) {
            int ce2 = min(32, cnt - (cin << 5));
            if (te < ce2) {
                const float4* rp = (const float4*)(erec + ((size_t)j * BCAP + (cin << 5) + te) * 16);
                nr0 = rp[0]; nr1 = rp[1]; nr2 = rp[2]; nr3 = rp[3];
            }
        }

        __syncthreads();

        {
            const int esg = te >> 4, e16 = te & 15;
            float rv[NROW][4];
            if (te < cntE) {
                float y0 = er0.w;
                float y0i = er1.x, y1i0 = er1.y, y1i1 = er1.z, y1i2 = er1.w;
                float M0 = er2.x, M1 = er2.y, M2 = er2.z, M4 = er2.w;
                float M5 = er3.x, M8 = er3.y;
                if (sub == 0) ECF[te] = er0.x;
#pragma unroll
                for (int up = 0; up < 4; ++up) {
                    float s = s4[up];
                    float v0 = vvx[3 * up], v1 = vvx[3 * up + 1], v2 = vvx[3 * up + 2];
                    rv[0][up] = s * y0;
                    rv[1][up] = v0 * y1i0 + v1 * y1i1 + v2 * y1i2;
                    rv[2][up] = s * y1i0;
                    rv[3][up] = s * y1i1;
                    rv[4][up] = s * y1i2;
                    rv[5][up] = v0 * y0i;
                    rv[6][up] = v1 * y0i;
                    rv[7][up] = v2 * y0i;
                    rv[8][up]  = v0 * M0 + v1 * M1 + v2 * M2;
                    rv[9][up]  = v0 * M1 + v1 * M4 + v2 * M5;
                    rv[10][up] = v0 * M2 + v1 * M5 + v2 * M8;
                }
            } else {
#pragma unroll
                for (int r = 0; r < NROW; ++r)
#pragma unroll
                    for (int up = 0; up < 4; ++up) rv[r][up] = 0.f;
            }
#pragma unroll
            for (int r = 0; r < NROW; ++r) {
                unsigned lo = pk_(rv[r][0], rv[r][1]);
                unsigned hi = pk_(rv[r][2], rv[r][3]);
                *(uint2*)&TB[((esg * NROW + r) * 16 + e16) * TSTR + u0] = make_uint2(lo, hi);
            }
        }
        __syncthreads();

        f32x4 cS0 = {0,0,0,0}, cS1 = {0,0,0,0}, cG0 = {0,0,0,0}, cG1 = {0,0,0,0};
        f32x4 cV[3][2];
#pragma unroll
        for (int k = 0; k < 3; ++k) { cV[k][0] = (f32x4){0,0,0,0}; cV[k][1] = (f32x4){0,0,0,0}; }

        #define LOADA(r) ({ FragU fa_; fa_.u = *(const uint4*)&TB[((sg * NROW + (r)) * 16 + col) * TSTR + quad * 8]; fa_.v; })

        bf16x8 a0 = LOADA(0), a1 = LOADA(1);
        cS0 = mfma_(a0, Bt[0][0], cS0); cS0 = mfma_(a1, Bt[1][0], cS0);
        cS1 = mfma_(a0, Bt[0][1], cS1); cS1 = mfma_(a1, Bt[1][1], cS1);
        cG0 = mfma_(a0, Bt[2][0], cG0); cG0 = mfma_(a1, Bt[3][0], cG0);
        cG1 = mfma_(a0, Bt[2][1], cG1); cG1 = mfma_(a1, Bt[3][1], cG1);
#pragma unroll
        for (int k = 0; k < 3; ++k) {
            bf16x8 ak;
            ak = LOADA(2 + k);
            cV[k][0] = mfma_(ak, Bt[4][0], cV[k][0]);
            cV[k][1] = mfma_(ak, Bt[4][1], cV[k][1]);
            ak = LOADA(5 + k);
            cV[k][0] = mfma_(ak, Bt[5][0], cV[k][0]);
            cV[k][1] = mfma_(ak, Bt[5][1], cV[k][1]);
            ak = LOADA(8 + k);
            cV[k][0] = mfma_(ak, Bt[6][0], cV[k][0]);
            cV[k][1] = mfma_(ak, Bt[6][1], cV[k][1]);
        }

        // epilogue: combine Ta + f*D, scale, store to slot-contiguous msg rows
        const int w = wh * 16 + col;
        const int sbase = j * BCAP + base;
#pragma unroll
        for (int reg = 0; reg < 4; ++reg) {
            int e = sg * 16 + quad * 4 + reg;
            if (e < cntE) {
                float f = ECF[e];
                float* mp = msg + (size_t)(sbase + e) * 160;
                mp[w]            = (cS0[reg] + f * cS1[reg]) * A0;
                mp[32 + w]       = (cG0[reg] + f * cG1[reg]) * A0;
                mp[64 + 3 * w]     = (cV[0][0][reg] + f * cV[0][1][reg]) * A1;
                mp[64 + 3 * w + 1] = (cV[1][0][reg] + f * cV[1][1][reg]) * A1;
                mp[64 + 3 * w + 2] = (cV[2][0][reg] + f * cV[2][1][reg]) * A1;
            }
        }
        #undef LOADA
        er0 = nr0; er1 = nr1; er2 = nr2; er3 = nr3;
    }
}

// ---- fused gather + node epilogue: 8 nodes per block (sortedD holds slots) ----
__global__ __launch_bounds__(256)
void node_kernel(const float* __restrict__ x, const float* __restrict__ Wss,
                 const float* __restrict__ Wsv, const float* __restrict__ msg,
                 const int* __restrict__ sortedD, const int* __restrict__ cntD,
                 float* __restrict__ out, int N)
{
    __shared__ float ms[8][160];
    const int tid = threadIdx.x;
    const int n0 = blockIdx.x * 8;
    const float IM = 0.1767766953f;  // 1/sqrt(32)

#pragma unroll
    for (int it = 0; it < 5; ++it) {
        int task = tid + it * 256;
        int nl = task / 160;
        int c = task - nl * 160;
        int n = n0 + nl;
        if (n < N) {
            int cd = cntD[n];
            int cc = cd < DCAP ? cd : DCAP;
            const int* sp = sortedD + n * DCAP;
            float s = 0.f;
            for (int i0 = 0; i0 < cc; i0 += 8) {
                int4 ia = *(const int4*)(sp + i0);
                int4 ib = *(const int4*)(sp + i0 + 4);
                int id[8] = { ia.x, ia.y, ia.z, ia.w, ib.x, ib.y, ib.z, ib.w };
                float p[8];
#pragma unroll
                for (int k = 0; k < 8; ++k)
                    p[k] = (i0 + k < cc) ? msg[(size_t)id[k] * 160 + c] : 0.f;
#pragma unroll
                for (int k = 0; k < 8; ++k) s += p[k];
            }
            ms[nl][c] = s / fmaxf((float)cd, 1.f);
        }
    }
    __syncthreads();

#pragma unroll
    for (int it = 0; it < 2; ++it) {
        int task = tid + it * 256;
        int nl = task >> 6, col = task & 63;
        int n = n0 + nl;
        if (n >= N) continue;
        const float* m  = ms[nl];
        const float* xp = x + (size_t)n * 128;
        if (col < 32) {
            int w = col;
            float mval = m[w];
            float gs = mval * sigmoidf_(mval);
            float dot = 0.f;
#pragma unroll 4
            for (int u = 0; u < 32; ++u) dot += xp[u] * Wss[u * 32 + w];
            float hs = gs + dot * IM;
            out[(size_t)n * 64 + w] = sqrtf(hs * hs + 1e-12f);
        } else {
            int w = col - 32;
            float gate = sigmoidf_(m[32 + w]);
            float g0 = m[64 + 3 * w + 0] * gate;
            float g1 = m[64 + 3 * w + 1] * gate;
            float g2 = m[64 + 3 * w + 2] * gate;
            float d0 = 0.f, d1 = 0.f, d2 = 0.f;
#pragma unroll 4
            for (int u = 0; u < 32; ++u) {
                float wvv = Wsv[u * 32 + w];
                d0 += xp[32 + 3 * u + 0] * wvv;
                d1 += xp[32 + 3 * u + 1] * wvv;
                d2 += xp[32 + 3 * u + 2] * wvv;
            }
            float h0 = g0 + d0 * IM, h1 = g1 + d1 * IM, h2 = g2 + d2 * IM;
            out[(size_t)n * 64 + 32 + w] = sqrtf(h0 * h0 + h1 * h1 + h2 * h2 + 1e-12f);
        }
    }
}

extern "C" void kernel_launch(void* const* d_in, const int* in_sizes, int n_in,
                              void* d_out, int out_size, void* d_ws, size_t ws_size,
                              hipStream_t stream)
{
    const float* x    = (const float*)d_in[0];
    const float* ea   = (const float*)d_in[1];
    const float* elen = (const float*)d_in[2];
    const int*   esrc = (const int*)d_in[3];
    const int*   edst = (const int*)d_in[4];
    const float* W1   = (const float*)d_in[5];
    const float* W2   = (const float*)d_in[6];
    const float* Wss  = (const float*)d_in[7];
    const float* Wsv  = (const float*)d_in[8];
    float* out = (float*)d_out;

    const int N = in_sizes[0] / 128;   // 4096
    const int E = in_sizes[2];         // 32768

    float* Bpkf   = (float*)d_ws;                       // 256*28*64 uint4 (7.3 MB)
    float* msg    = Bpkf + (size_t)256 * 28 * 64 * 4;   // 256*BCAP*160 floats (42 MB, slot-indexed)
    float* erec   = msg + (size_t)256 * BCAP * 160;     // 256*BCAP*16 floats (4 MB)
    int*   cntL   = (int*)(erec + (size_t)256 * BCAP * 16); // 256
    int*   cntD   = cntL + 256;                         // N (4096)
    int*   sortedD= cntD + N;                           // N*DCAP
    uint4* Bpk    = (uint4*)Bpkf;

    hipMemsetAsync(cntL, 0, (size_t)(256 + N) * sizeof(int), stream);

    prep_kernel<<<TPACK + (E + 255) / 256, 256, 0, stream>>>(W1, W2, elen, esrc, edst, ea, Bpk, cntL, cntD, erec, sortedD, E);
    fold_kernel<<<NIVL * 2, 256, 0, stream>>>(x, cntL, erec, Bpk, msg);
    node_kernel<<<(N + 7) / 8, 256, 0, stream>>>(x, Wss, Wsv, msg, sortedD, cntD, out, N);
}